// Round 5
// baseline (233.462 us; speedup 1.0000x reference)
//
#include <hip/hip_runtime.h>

// Problem constants (from reference)
#define CC 9605
#define BB 2048
#define LL 8
#define CAND_MAX 384
#define NEGF (-1e30f)
#define NBLK 512            // persistent blocks; each handles BB/NBLK rows
#define ROWSPB (BB / NBLK)  // 4

// d_ws layout (unsigned words):
//   wsu[0] = wl entry count (atomic)
//   wsu[1] = dtype sniff flags (atomic OR)
//   wsu[4 .. 4+2048) = whitelist entries (col<<8 | mask)
//   byte offset 16384: float partials[BB]
#define WS_PARTIALS_OFF 16384

__device__ __forceinline__ unsigned enc_f(float f) {
  unsigned u = __float_as_uint(f);
  return (u & 0x80000000u) ? ~u : (u | 0x80000000u);
}
__device__ __forceinline__ float dec_u(unsigned e) {
  unsigned u = (e & 0x80000000u) ? (e & 0x7fffffffu) : ~e;
  return __uint_as_float(u);
}
__device__ __forceinline__ float sigm(float z) {
  return 1.0f / (1.0f + __expf(-z));
}
// popcount of mask bits strictly below this lane (64-lane prefix)
__device__ __forceinline__ unsigned prefix_lt(unsigned long long m) {
  unsigned r = __builtin_amdgcn_mbcnt_lo((unsigned)m, 0u);
  return __builtin_amdgcn_mbcnt_hi((unsigned)(m >> 32), r);
}
// Raw workgroup barrier WITHOUT the vmcnt(0) drain __syncthreads emits.
// All cross-wave traffic in loss_kernel is LDS -> lgkmcnt(0) + s_barrier is
// sufficient; prefetched global loads stay in flight across it.
__device__ __forceinline__ void syncb() {
  __builtin_amdgcn_sched_barrier(0);
  asm volatile("s_waitcnt lgkmcnt(0)" ::: "memory");
  __builtin_amdgcn_s_barrier();
  __builtin_amdgcn_sched_barrier(0);
}

// ---- dtype sniff (word loads): byte signatures over the raw wl buffer ----
//   u8  : byte==1 at offsets %4 != 0        -> flag 1 (and 2)
//   i32 : byte==1 only at offsets %4 == 0   -> flag 2
//   f32 : 0x3f at %4==3, never byte==1      -> flag 8
//   bf16: 0x3f at odd offsets incl %4==1    -> flag 4 (and 8)
__global__ void wl_sniff(const unsigned* __restrict__ wlw,
                         unsigned* __restrict__ wsu) {
  const int nwords = (LL * CC) / 4;  // 76840 % 4 == 0
  const int stride = gridDim.x * blockDim.x;
  unsigned f = 0u;
  for (int j = blockIdx.x * blockDim.x + threadIdx.x; j < nwords; j += stride) {
    unsigned w = wlw[j];
#pragma unroll
    for (int k = 0; k < 4; ++k) {
      unsigned b = (w >> (8 * k)) & 255u;
      if (b == 1u)    { f |= 2u; if (k != 0) f |= 1u; }
      if (b == 0x3fu) { f |= 8u; if (k == 1) f |= 4u; }
    }
  }
#pragma unroll
  for (int off = 32; off >= 1; off >>= 1) f |= __shfl_xor(f, off, 64);
  if ((threadIdx.x & 63) == 0 && f) atomicOr(&wsu[1], f);
}

__global__ void wl_compact(const unsigned char* __restrict__ wl,
                           unsigned* __restrict__ wsu) {
  const int tid = threadIdx.x;
  const int lane = tid & 63;
  const int c = blockIdx.x * 256 + tid;
  const unsigned g = wsu[1];
  const int dt = (g & 1u) ? 0 : (g & 4u) ? 3 : (g & 2u) ? 1 : (g & 8u) ? 2 : 0;
  const int* wl32 = (const int*)wl;
  const float* wlf = (const float*)wl;
  const unsigned short* wlh = (const unsigned short*)wl;
  unsigned m = 0u;
  if (c < CC) {
#pragma unroll
    for (int l = 0; l < LL; ++l) {
      int j = l * CC + c;
      bool on;
      if (dt == 0) on = (wl[j] != 0);
      else if (dt == 1) on = (wl32[j] != 0);
      else if (dt == 2) on = (wlf[j] != 0.0f);
      else on = (wlh[j] != 0);
      if (on) m |= (1u << l);
    }
  }
  unsigned long long bal = __ballot(m != 0u);
  if (bal) {
    unsigned wcnt = (unsigned)__popcll(bal);
    unsigned basep = 0u;
    if (lane == 0) basep = atomicAdd(&wsu[0], wcnt);
    basep = __shfl(basep, 0, 64);
    if (m) {
      unsigned pos = basep + (unsigned)__popcll(bal & ((1ull << lane) - 1ull));
      if (pos < 2048u) wsu[4 + pos] = ((unsigned)c << 8) | m;
    }
  }
}

// encode one float4 into one uint4, folding into running max `mx`
#define ENCMAX(U, T)                                            \
  do {                                                          \
    U.x = enc_f(T.x); U.y = enc_f(T.y);                         \
    U.z = enc_f(T.z); U.w = enc_f(T.w);                         \
    mx = max(mx, max(max(U.x, U.y), max(U.z, U.w)));            \
  } while (0)

#define CNT4(U, T)                                              \
  (((U.x >= (T)) ? 1u : 0u) + ((U.y >= (T)) ? 1u : 0u) +        \
   ((U.z >= (T)) ? 1u : 0u) + ((U.w >= (T)) ? 1u : 0u))

// uniform block-wide count of encoded row values >= T (result in RES)
// wave sum via 5 ballot bit-planes (cnt <= 21 fits 5 bits) -- no DS ops.
#define BLK_COUNT(T, RES)                                       \
  do {                                                          \
    unsigned _c = CNT4(u0, (T)) + CNT4(u1, (T)) + CNT4(u2, (T)) \
                + CNT4(u3, (T)) + CNT4(u4, (T))                 \
                + ((et >= (T)) ? 1u : 0u);                      \
    unsigned _w = (unsigned)__popcll(__ballot(_c & 1u));        \
    _w += (unsigned)__popcll(__ballot(_c & 2u)) << 1;           \
    _w += (unsigned)__popcll(__ballot(_c & 4u)) << 2;           \
    _w += (unsigned)__popcll(__ballot(_c & 8u)) << 3;           \
    _w += (unsigned)__popcll(__ballot(_c & 16u)) << 4;          \
    syncb(); /* guard sh_redC reuse */                          \
    if (lane == 0) sh_redC[wid] = _w;                           \
    syncb();                                                    \
    RES = sh_redC[0] + sh_redC[1] + sh_redC[2] + sh_redC[3] +   \
          sh_redC[4] + sh_redC[5] + sh_redC[6] + sh_redC[7];    \
  } while (0)

#define EMIT(V)                                                 \
  do {                                                          \
    if ((V) >= lo) sh_cand[pos++] = (V);                        \
  } while (0)

// Full per-row selection + loss (R4 logic, raw barriers). Inlined 4x.
__device__ __forceinline__ void process_row(
    const float* __restrict__ x, const float* __restrict__ y,
    const unsigned* __restrict__ ents, unsigned nu, int r,
    int tid, int lane, int wid,
    float4 t0, float4 t1, float4 t2, float4 t3, float4 t4,
    bool v4, bool ht, float tv, float gx, float gy,
    bool h0, unsigned mk0,
    unsigned* sh_cand, unsigned* sh_redM, unsigned* sh_redC,
    unsigned* sh_cnt, float (*sh_wl)[10], float* __restrict__ partials) {
  const long long base = (long long)r * CC;

  // ---- encode into named registers, track max ----
  unsigned mx = 0u;
  uint4 u0, u1, u2, u3, u4;
  ENCMAX(u0, t0);
  ENCMAX(u1, t1);
  ENCMAX(u2, t2);
  ENCMAX(u3, t3);
  if (v4) {
    ENCMAX(u4, t4);
  } else {
    u4.x = 0u; u4.y = 0u; u4.z = 0u; u4.w = 0u;  // raw 0 < enc of any float
  }
  unsigned et = 0u;
  if (ht) { et = enc_f(tv); mx = max(mx, et); }
  if (tid == 0) *sh_cnt = 0u;

  // ---- block max ----
  mx = max(mx, __shfl_xor(mx, 32, 64));
  mx = max(mx, __shfl_xor(mx, 16, 64));
  mx = max(mx, __shfl_xor(mx, 8, 64));
  mx = max(mx, __shfl_xor(mx, 4, 64));
  mx = max(mx, __shfl_xor(mx, 2, 64));
  mx = max(mx, __shfl_xor(mx, 1, 64));
  if (lane == 0) sh_redM[wid] = mx;
  syncb();
  unsigned Emax = sh_redM[0];
#pragma unroll
  for (int w = 1; w < 8; ++w) Emax = max(Emax, sh_redM[w]);

  // ---- find window [lo,hi) with count(>=lo)>=11 > count(>=hi) ----
  unsigned E11 = 0u;
  bool done = false;
  unsigned lo = (Emax > (1u << 23)) ? (Emax - (1u << 23)) : 1u;
  unsigned hi = Emax + 1u;
  unsigned c;
  BLK_COUNT(lo, c);
  while (c < 11u && lo > 1u) {   // uniform: c, lo derived from shared data
    hi = lo;
    lo = (lo > (1u << 23)) ? (lo - (1u << 23)) : 1u;
    BLK_COUNT(lo, c);
  }
  while (c > CAND_MAX) {  // rare: bisect (tie-collapse => exact answer)
    if (hi - lo <= 1u) { E11 = lo; done = true; break; }
    unsigned mid = lo + ((hi - lo) >> 1);
    unsigned cm;
    BLK_COUNT(mid, cm);
    if (cm >= 11u) { lo = mid; c = cm; } else { hi = mid; }
  }

  // ---- compact candidates (>= lo) into sh_cand; prefix via mbcnt ----
  if (!done) {
    unsigned nloc = CNT4(u0, lo) + CNT4(u1, lo) + CNT4(u2, lo) +
                    CNT4(u3, lo) + CNT4(u4, lo) + ((et >= lo) ? 1u : 0u);
    unsigned long long m0 = __ballot(nloc & 1u);
    unsigned long long m1 = __ballot(nloc & 2u);
    unsigned long long m2 = __ballot(nloc & 4u);
    unsigned long long m3 = __ballot(nloc & 8u);
    unsigned long long m4 = __ballot(nloc & 16u);
    unsigned wtot = (unsigned)__popcll(m0) + ((unsigned)__popcll(m1) << 1) +
                    ((unsigned)__popcll(m2) << 2) +
                    ((unsigned)__popcll(m3) << 3) +
                    ((unsigned)__popcll(m4) << 4);
    unsigned pre = prefix_lt(m0) + (prefix_lt(m1) << 1) +
                   (prefix_lt(m2) << 2) + (prefix_lt(m3) << 3) +
                   (prefix_lt(m4) << 4);
    unsigned basep = 0u;
    if (lane == 0) basep = atomicAdd(sh_cnt, wtot);
    basep = (unsigned)__builtin_amdgcn_readfirstlane((int)basep);
    unsigned pos = basep + pre;                  // exclusive offset
    EMIT(u0.x); EMIT(u0.y); EMIT(u0.z); EMIT(u0.w);
    EMIT(u1.x); EMIT(u1.y); EMIT(u1.z); EMIT(u1.w);
    EMIT(u2.x); EMIT(u2.y); EMIT(u2.z); EMIT(u2.w);
    EMIT(u3.x); EMIT(u3.y); EMIT(u3.z); EMIT(u3.w);
    EMIT(u4.x); EMIT(u4.y); EMIT(u4.z); EMIT(u4.w);
    EMIT(et);
    syncb();
  }

  // ---- whitelist reduce for ALL waves (overlaps wave 0's search) ----
  {
    float lm[8];
#pragma unroll
    for (int l = 0; l < 8; ++l) lm[l] = NEGF;
    unsigned pmask = 0u;  // bits0-7: label present; bits8-15: has positive
    if (h0) {
      pmask |= mk0;
      if (gy > 0.0f) pmask |= (mk0 << 8);
#pragma unroll
      for (int l = 0; l < 8; ++l)
        if ((mk0 >> l) & 1u) lm[l] = fmaxf(lm[l], gx);
    }
    // safety net (nu <= ~400 here; loop normally never runs)
    for (unsigned e = (unsigned)tid + 512u; e < nu; e += 512u) {
      unsigned ent = ents[e];
      unsigned mk = ent & 255u;
      float xv = x[base + (ent >> 8)];
      float yv = y[base + (ent >> 8)];
      pmask |= mk;
      if (yv > 0.0f) pmask |= (mk << 8);
#pragma unroll
      for (int l = 0; l < 8; ++l)
        if ((mk >> l) & 1u) lm[l] = fmaxf(lm[l], xv);
    }
#pragma unroll
    for (int off = 32; off >= 1; off >>= 1) {
      pmask |= __shfl_xor(pmask, off, 64);
#pragma unroll
      for (int l = 0; l < 8; ++l)
        lm[l] = fmaxf(lm[l], __shfl_xor(lm[l], off, 64));
    }
    if (lane == 0) {
#pragma unroll
      for (int l = 0; l < 8; ++l) sh_wl[wid][l] = lm[l];
      sh_wl[wid][8] = __uint_as_float(pmask);
    }
  }

  // ---- wave 0: exact 11th-largest via value binary search (ballots only) --
  if (!done && wid == 0) {
    unsigned c0 = ((unsigned)lane < c) ? sh_cand[lane] : 0u;
    unsigned c1 = ((unsigned)lane + 64u < c) ? sh_cand[lane + 64u] : 0u;
    unsigned c2 = ((unsigned)lane + 128u < c) ? sh_cand[lane + 128u] : 0u;
    unsigned c3 = ((unsigned)lane + 192u < c) ? sh_cand[lane + 192u] : 0u;
    unsigned c4 = ((unsigned)lane + 256u < c) ? sh_cand[lane + 256u] : 0u;
    unsigned c5 = ((unsigned)lane + 320u < c) ? sh_cand[lane + 320u] : 0u;
    unsigned blo = lo, bhi = hi;
    while (bhi - blo > 1u) {
      unsigned mid = blo + ((bhi - blo) >> 1);
      unsigned cnt = (unsigned)__popcll(__ballot(c0 >= mid)) +
                     (unsigned)__popcll(__ballot(c1 >= mid)) +
                     (unsigned)__popcll(__ballot(c2 >= mid)) +
                     (unsigned)__popcll(__ballot(c3 >= mid)) +
                     (unsigned)__popcll(__ballot(c4 >= mid)) +
                     (unsigned)__popcll(__ballot(c5 >= mid));
      if (cnt >= 11u) blo = mid; else bhi = mid;
    }
    E11 = blo;  // largest T with count(>=T) >= 11 == the 11th largest value
  }
  syncb();

  // ---- epilogue on thread 0: per-row partial (E11 is in its regs) ----
  if (tid == 0) {
    float LM[8];
    unsigned PM = 0u;
#pragma unroll
    for (int l = 0; l < 8; ++l) LM[l] = NEGF;
    for (int w = 0; w < 8; ++w) {
#pragma unroll
      for (int l = 0; l < 8; ++l) LM[l] = fmaxf(LM[l], sh_wl[w][l]);
      PM |= __float_as_uint(sh_wl[w][8]);
    }
    unsigned PR = PM & 255u, PO = (PM >> 8) & 255u;
    float thres = fmaxf(sigm(dec_u(E11)), 0.5f);
    float cmax = NEGF, imax = NEGF, umax = NEGF;
#pragma unroll
    for (int l = 0; l < 8; ++l) {
      if ((PR >> l) & 1u) {
        float ml = sigm(LM[l]);
        umax = fmaxf(umax, ml);
        if ((PO >> l) & 1u) cmax = fmaxf(cmax, ml);
        else imax = fmaxf(imax, ml);
      }
    }
    bool anyc = (PO != 0u);
    bool anyi = (PO != 255u);  // L == 8 labels always exist
    float x1 = anyc ? cmax : thres;
    float x2 = anyc ? (anyi ? fmaxf(imax, thres) : thres)
                    : ((nu > 0u) ? umax : NEGF);
    float coef = anyc ? 1.0f : 0.5f;
    float dd = x2 - x1 + 0.1f;
    float rank = ((dd > 0.0f) ? 2.0f : 1.0f) * sigm(10.0f * dd);
    partials[r] = coef * rank;
  }
}

// Issue all loads for row R into slot-S registers (S in {A,B}).
#define LOADROW(S, R)                                                     \
  do {                                                                    \
    const int _r = (R);                                                   \
    const long long _base = (long long)_r * CC;                           \
    const int _soff = (4 - (_r & 3)) & 3;                                 \
    const int _ng = (CC - _soff) >> 2;                                    \
    const int _me = CC - (_ng << 2); /* soff + tail count */              \
    const float4* _vp = (const float4*)(x + _base + _soff);               \
    t##S##0 = _vp[tid];                                                   \
    t##S##1 = _vp[tid + 512];                                             \
    t##S##2 = _vp[tid + 1024];                                            \
    t##S##3 = _vp[tid + 1536];                                            \
    v4##S = (tid + 2048 < _ng);                                           \
    if (v4##S) t##S##4 = _vp[tid + 2048];                                 \
    ht##S = (tid < _me);                                                  \
    if (ht##S) {                                                          \
      int _tc = (tid < _soff) ? tid                                       \
                              : (_soff + (_ng << 2) + (tid - _soff));     \
      tv##S = x[_base + _tc];                                             \
    }                                                                     \
    if (h0) { gx##S = x[_base + wlcol]; gy##S = y[_base + wlcol]; }       \
  } while (0)

// Persistent blocks, 4 rows each, 1-deep row prefetch: while row k is in
// its (register-only + LDS) selection phase, row k+1's 21 vector loads and
// gathers are already in flight. Raw s_barrier (syncb) everywhere so the
// compiler's __syncthreads vmcnt(0) drain cannot kill the prefetch.
// launch_bounds(512,4): VGPR cap 128 guarantees 2 blocks/CU (est ~96 live).
__global__ __launch_bounds__(512, 4) void loss_kernel(
    const float* __restrict__ x, const float* __restrict__ y,
    const unsigned* __restrict__ wsu, float* __restrict__ partials) {
  __shared__ unsigned sh_cand[CAND_MAX];
  __shared__ unsigned sh_redM[8];
  __shared__ unsigned sh_redC[8];
  __shared__ unsigned sh_cnt;
  __shared__ float sh_wl[8][10];

  const int tid = threadIdx.x;
  const int lane = tid & 63;
  const int wid = tid >> 6;
  const int bid = blockIdx.x;

  // whitelist entry (row-independent) loaded once
  const unsigned nu = min(wsu[0], 2048u);
  const unsigned* ents = wsu + 4;
  const bool h0 = (unsigned)tid < nu;
  unsigned ent0 = 0u;
  if (h0) ent0 = ents[tid];
  const int wlcol = (int)(ent0 >> 8);
  const unsigned mk0 = ent0 & 255u;

  // two row slots
  float4 tA0, tA1, tA2, tA3, tA4 = make_float4(0.f, 0.f, 0.f, 0.f);
  float4 tB0, tB1, tB2, tB3, tB4 = make_float4(0.f, 0.f, 0.f, 0.f);
  bool v4A = false, htA = false, v4B = false, htB = false;
  float tvA = 0.f, gxA = NEGF, gyA = 0.f;
  float tvB = 0.f, gxB = NEGF, gyB = 0.f;

  const int r0 = bid;
  LOADROW(A, r0);                    // prologue: row 0 loads
  LOADROW(B, r0 + NBLK);             // prefetch row 1
  process_row(x, y, ents, nu, r0, tid, lane, wid,
              tA0, tA1, tA2, tA3, tA4, v4A, htA, tvA, gxA, gyA,
              h0, mk0, sh_cand, sh_redM, sh_redC, &sh_cnt, sh_wl, partials);
  LOADROW(A, r0 + 2 * NBLK);         // prefetch row 2
  process_row(x, y, ents, nu, r0 + NBLK, tid, lane, wid,
              tB0, tB1, tB2, tB3, tB4, v4B, htB, tvB, gxB, gyB,
              h0, mk0, sh_cand, sh_redM, sh_redC, &sh_cnt, sh_wl, partials);
  LOADROW(B, r0 + 3 * NBLK);         // prefetch row 3
  process_row(x, y, ents, nu, r0 + 2 * NBLK, tid, lane, wid,
              tA0, tA1, tA2, tA3, tA4, v4A, htA, tvA, gxA, gyA,
              h0, mk0, sh_cand, sh_redM, sh_redC, &sh_cnt, sh_wl, partials);
  process_row(x, y, ents, nu, r0 + 3 * NBLK, tid, lane, wid,
              tB0, tB1, tB2, tB3, tB4, v4B, htB, tvB, gxB, gyB,
              h0, mk0, sh_cand, sh_redM, sh_redC, &sh_cnt, sh_wl, partials);
}

__global__ void final_reduce(const float* __restrict__ partials,
                             float* __restrict__ out) {
  __shared__ float sh[4];
  const int tid = threadIdx.x;
  const int lane = tid & 63;
  const int wid = tid >> 6;
  float s = 0.0f;
  for (int i = tid; i < BB; i += 256) s += partials[i];
#pragma unroll
  for (int off = 32; off >= 1; off >>= 1) s += __shfl_xor(s, off, 64);
  if (lane == 0) sh[wid] = s;
  __syncthreads();
  if (tid == 0) out[0] = (sh[0] + sh[1] + sh[2] + sh[3]) * (1.0f / (float)BB);
}

extern "C" void kernel_launch(void* const* d_in, const int* in_sizes, int n_in,
                              void* d_out, int out_size, void* d_ws,
                              size_t ws_size, hipStream_t stream) {
  const float* x = (const float*)d_in[0];
  const float* y = (const float*)d_in[1];
  // d_in[2] (y_neg) is faithfully ignored — it never affects the loss.
  const unsigned char* wl = (const unsigned char*)d_in[3];
  float* out = (float*)d_out;
  unsigned* wsu = (unsigned*)d_ws;
  float* partials = (float*)((char*)d_ws + WS_PARTIALS_OFF);

  hipMemsetAsync(d_ws, 0, 16, stream);  // zero wsu[0..3]
  wl_sniff<<<64, 256, 0, stream>>>((const unsigned*)wl, wsu);
  wl_compact<<<(CC + 255) / 256, 256, 0, stream>>>(wl, wsu);
  loss_kernel<<<NBLK, 512, 0, stream>>>(x, y, wsu, partials);
  final_reduce<<<1, 256, 0, stream>>>(partials, out);
}